// Round 1
// baseline (96.318 us; speedup 1.0000x reference)
//
#include <hip/hip_runtime.h>
#include <math.h>

#define N_SUBWORDS 8192
#define N_WORDS    6000
#define HIDDEN     1024

// ---------------------------------------------------------------------------
// Pass 1: scores[s] = hs[s,:] . w_attn + b   (one wave per subword row)
//
// Lane l owns float4 chunks {l + 64j : j=0..3} of the 1024-dim row
// (4 KB row = 256 float4, coalesced). One 6-step butterfly per ROW --
// 8192 fully parallel waves, instead of one butterfly per span element
// per word as in the previous fused kernel. Also warms L2/LLC with hs
// immediately before the pooling pass.
// ---------------------------------------------------------------------------
__global__ __launch_bounds__(256) void coref_score_kernel(
    const float* __restrict__ hs,      // [N_SUBWORDS, HIDDEN]
    const float* __restrict__ w_attn,  // [HIDDEN]
    const float* __restrict__ b_attn,  // [1]
    float*       __restrict__ scores)  // [N_SUBWORDS]
{
    const int tid  = threadIdx.x;
    const int lane = tid & 63;
    const int row  = blockIdx.x * 4 + (tid >> 6);   // 4 waves / block
    if (row >= N_SUBWORDS) return;

    const float4* __restrict__ wvp = (const float4*)w_attn;
    const float4* __restrict__ rp  = (const float4*)(hs + (size_t)row * HIDDEN);

    float part = 0.f;
#pragma unroll
    for (int j = 0; j < 4; ++j) {
        const float4 h  = rp[lane + 64 * j];
        const float4 wv = wvp[lane + 64 * j];
        part += h.x * wv.x + h.y * wv.y + h.z * wv.z + h.w * wv.w;
    }

    // wave-64 butterfly: lane 0 ends with the full dot product
#pragma unroll
    for (int off = 32; off > 0; off >>= 1)
        part += __shfl_xor(part, off, 64);

    if (lane == 0)
        scores[row] = part + b_attn[0];
}

// ---------------------------------------------------------------------------
// Pass 2: per-word softmax-pool with precomputed scalar scores.
//
// One wave per word. Span scores are scalar broadcast loads (L2-hot,
// 32 KB table). Two tiny scalar loops (max, then exp+accumulate) --
// NO cross-lane reduce, NO online-rescale loop-carried chain. The
// accumulate loop's only carried dep is 16 independent FMAs, so the
// 4 KB row loads software-pipeline freely.
// ---------------------------------------------------------------------------
__global__ __launch_bounds__(256) void coref_pool_kernel(
    const float* __restrict__ hs,      // [N_SUBWORDS, HIDDEN]
    const int*   __restrict__ starts,  // [N_WORDS]
    const int*   __restrict__ ends,    // [N_WORDS] inclusive
    const float* __restrict__ scores,  // [N_SUBWORDS]
    float*       __restrict__ out)     // [N_WORDS, HIDDEN]
{
    const int tid  = threadIdx.x;
    const int lane = tid & 63;
    const int w    = blockIdx.x * 4 + (tid >> 6);   // 4 waves / block
    if (w >= N_WORDS) return;

    const int s0 = starts[w];
    const int s1 = ends[w];   // inclusive, >= s0

    // span max (avg span length ~1.65; loads independent, fmax chain cheap)
    float m = -INFINITY;
    for (int s = s0; s <= s1; ++s)
        m = fmaxf(m, scores[s]);

    // weighted accumulate with fixed max
    float  l = 0.f;
    float4 acc[4];
#pragma unroll
    for (int j = 0; j < 4; ++j)
        acc[j] = make_float4(0.f, 0.f, 0.f, 0.f);

    for (int s = s0; s <= s1; ++s) {
        const float p = __expf(scores[s] - m);
        l += p;
        const float4* __restrict__ row = (const float4*)(hs + (size_t)s * HIDDEN);
#pragma unroll
        for (int j = 0; j < 4; ++j) {
            const float4 h = row[lane + 64 * j];
            acc[j].x += p * h.x;
            acc[j].y += p * h.y;
            acc[j].z += p * h.z;
            acc[j].w += p * h.w;
        }
    }

    const float inv_l = 1.f / l;
    float4* __restrict__ orow = (float4*)(out + (size_t)w * HIDDEN);
#pragma unroll
    for (int j = 0; j < 4; ++j) {
        float4 o;
        o.x = acc[j].x * inv_l;
        o.y = acc[j].y * inv_l;
        o.z = acc[j].z * inv_l;
        o.w = acc[j].w * inv_l;
        orow[lane + 64 * j] = o;
    }
}

extern "C" void kernel_launch(void* const* d_in, const int* in_sizes, int n_in,
                              void* d_out, int out_size, void* d_ws, size_t ws_size,
                              hipStream_t stream) {
    const float* hs     = (const float*)d_in[0];  // [8192*1024] f32
    const int*   starts = (const int*)d_in[1];    // [6000]
    const int*   ends   = (const int*)d_in[2];    // [6000]
    const float* w_attn = (const float*)d_in[3];  // [1024] f32
    const float* b_attn = (const float*)d_in[4];  // [1] f32
    float*       out    = (float*)d_out;          // [6000*1024] f32
    float*       scores = (float*)d_ws;           // [8192] f32 (32 KB workspace)

    // Pass 1: 8192 rows, one wave each, 4 waves/block -> 2048 blocks
    coref_score_kernel<<<dim3(N_SUBWORDS / 4), dim3(256), 0, stream>>>(
        hs, w_attn, b_attn, scores);

    // Pass 2: 6000 words, one wave each, 4 waves/block -> 1500 blocks
    coref_pool_kernel<<<dim3((N_WORDS + 3) / 4), dim3(256), 0, stream>>>(
        hs, starts, ends, scores, out);
}

// Round 2
// 89.645 us; speedup vs baseline: 1.0744x; 1.0744x over previous
//
#include <hip/hip_runtime.h>
#include <math.h>

#define N_SUBWORDS 8192
#define N_WORDS    6000
#define HIDDEN     1024

// One WAVE per word, single pass over the span rows (minimal traffic:
// hs read once ~32 MB, out written once ~24 MB).
//
// vs the previous fused version:
//  - span-1 words (about half: random sorted starts, mean gap 1.37) take a
//    pure copy fast path: softmax over one element == 1, out = row. No dot,
//    no butterfly, no exp.
//  - longer spans are processed in chunks of 4: the 6-step shfl_xor
//    butterflies for the 4 elements are interleaved (ILP-4, ~6 swizzle
//    latencies per chunk instead of per element), and the online-softmax
//    rescale of acc happens once per CHUNK, not once per element. This cuts
//    the serial latency chain of the longest-span (~12) tail waves ~3-4x.
__global__ __launch_bounds__(256) void coref_fused_kernel(
    const float* __restrict__ hs,      // [N_SUBWORDS, HIDDEN]
    const int*   __restrict__ starts,  // [N_WORDS]
    const int*   __restrict__ ends,    // [N_WORDS] inclusive
    const float* __restrict__ w_attn,  // [HIDDEN]
    const float* __restrict__ b_attn,  // [1]
    float*       __restrict__ out)     // [N_WORDS, HIDDEN]
{
    const int tid  = threadIdx.x;
    const int lane = tid & 63;
    // wave-uniform word id in an SGPR -> s_load for starts/ends, uniform branches
    const int w = __builtin_amdgcn_readfirstlane(blockIdx.x * 4 + (tid >> 6));
    if (w >= N_WORDS) return;

    const int s0 = starts[w];
    const int s1 = ends[w];   // inclusive, >= s0

    const float4* __restrict__ hs4  = (const float4*)hs;
    float4*       __restrict__ orow = (float4*)(out + (size_t)w * HIDDEN);

    // ---- fast path: single-subword word -> softmax of 1 element == copy ----
    if (s1 <= s0) {
        const float4* __restrict__ row = hs4 + (size_t)s0 * (HIDDEN / 4);
#pragma unroll
        for (int j = 0; j < 4; ++j)
            orow[lane + 64 * j] = row[lane + 64 * j];
        return;
    }

    // ---- general path ----
    const float4* __restrict__ wvp = (const float4*)w_attn;
    float4 wv[4];
#pragma unroll
    for (int j = 0; j < 4; ++j)
        wv[j] = wvp[lane + 64 * j];
    const float b = b_attn[0];

    float  m = -INFINITY, l = 0.f;
    float4 acc[4];
#pragma unroll
    for (int j = 0; j < 4; ++j)
        acc[j] = make_float4(0.f, 0.f, 0.f, 0.f);

    for (int s = s0; s <= s1; s += 4) {
        const int C = (s1 - s + 1 < 4) ? (s1 - s + 1) : 4;

        // load up to 4 rows into registers, per-lane partial dots
        float4 h[4][4];
        float  part[4];
#pragma unroll
        for (int c = 0; c < 4; ++c) {
            part[c] = 0.f;
            if (c < C) {
                const float4* __restrict__ row =
                    hs4 + (size_t)(s + c) * (HIDDEN / 4);
#pragma unroll
                for (int j = 0; j < 4; ++j) {
                    h[c][j] = row[lane + 64 * j];
                    part[c] += h[c][j].x * wv[j].x + h[c][j].y * wv[j].y +
                               h[c][j].z * wv[j].z + h[c][j].w * wv[j].w;
                }
            }
        }

        // 6-round wave-64 butterflies, interleaved across the chunk (ILP-4)
#pragma unroll
        for (int off = 32; off > 0; off >>= 1) {
#pragma unroll
            for (int c = 0; c < 4; ++c)
                part[c] += __shfl_xor(part[c], off, 64);
        }

        // chunk max, then ONE online rescale for the whole chunk
        float cm = -INFINITY;
#pragma unroll
        for (int c = 0; c < 4; ++c)
            if (c < C) cm = fmaxf(cm, part[c] + b);

        const float mn    = fmaxf(m, cm);
        const float alpha = __expf(m - mn);   // first chunk: exp(-inf)=0, acc=0 -> ok
        l *= alpha;
#pragma unroll
        for (int j = 0; j < 4; ++j) {
            acc[j].x *= alpha; acc[j].y *= alpha;
            acc[j].z *= alpha; acc[j].w *= alpha;
        }

        float p[4];
#pragma unroll
        for (int c = 0; c < 4; ++c) {
            p[c] = (c < C) ? __expf(part[c] + b - mn) : 0.f;
            l += p[c];
        }
#pragma unroll
        for (int c = 0; c < 4; ++c) {
            if (c < C) {
#pragma unroll
                for (int j = 0; j < 4; ++j) {
                    acc[j].x += p[c] * h[c][j].x;
                    acc[j].y += p[c] * h[c][j].y;
                    acc[j].z += p[c] * h[c][j].z;
                    acc[j].w += p[c] * h[c][j].w;
                }
            }
        }
        m = mn;
    }

    const float inv_l = 1.f / l;
#pragma unroll
    for (int j = 0; j < 4; ++j) {
        float4 o;
        o.x = acc[j].x * inv_l;
        o.y = acc[j].y * inv_l;
        o.z = acc[j].z * inv_l;
        o.w = acc[j].w * inv_l;
        orow[lane + 64 * j] = o;
    }
}

extern "C" void kernel_launch(void* const* d_in, const int* in_sizes, int n_in,
                              void* d_out, int out_size, void* d_ws, size_t ws_size,
                              hipStream_t stream) {
    const float* hs     = (const float*)d_in[0];  // [8192*1024] f32
    const int*   starts = (const int*)d_in[1];    // [6000]
    const int*   ends   = (const int*)d_in[2];    // [6000]
    const float* w_attn = (const float*)d_in[3];  // [1024] f32
    const float* b_attn = (const float*)d_in[4];  // [1] f32
    float*       out    = (float*)d_out;          // [6000*1024] f32

    // 6000 words, one wave each, 4 waves per 256-thread block -> 1500 blocks
    coref_fused_kernel<<<dim3((N_WORDS + 3) / 4), dim3(256), 0, stream>>>(
        hs, starts, ends, w_attn, b_attn, out);
}